// Round 4
// baseline (553.863 us; speedup 1.0000x reference)
//
#include <hip/hip_runtime.h>

#define NPIX (8 * 256 * 256)

typedef float v4f __attribute__((ext_vector_type(4)));
typedef _Float16 v8h __attribute__((ext_vector_type(8)));
typedef _Float16 v4h __attribute__((ext_vector_type(4)));
typedef _Float16 h2 __attribute__((ext_vector_type(2)));

// ---- LDS / d_ws image byte offsets (prep writes this exact image) ----
#define OW0   0        // W0 frags: 8 frags  (t=0..7, s=0)           8192 B
#define OW1   8192     // W1 frags: 32 (t*4+s)                      32768 B
#define OW2   40960    // W2 frags: 32                              32768 B
#define OWT0  73728    // WT0 frags: 32                             32768 B
#define OWT1  106496   // WT1 frags: 32                             32768 B
#define OWSH  139264   // WSH frags: 4 (s=0..3), M padded to 16      4096 B
#define OWT2  143360   // WT2 frags: 4                               4096 B
#define OB0   147456   // f32 B0eff[8][128]                          4096 B
#define OB1   151552   // f32 [128]
#define OB2   152064   // f32 [128]
#define OBT0  152576   // f32 BT0eff[8][128]
#define OBT1  156672   // f32 [128]
#define OBSH  157184   // f32 [16] (row0 = bsh)
#define OBT2  157248   // f32 [16] (rows 0..2 = bt2)
#define IMG_BYTES 157312

// ============================ prep kernel ============================
__global__ void prep_kernel(
    const float* __restrict__ sc,  const float* __restrict__ tc,
    const float* __restrict__ ws0, const float* __restrict__ bs0,
    const float* __restrict__ ws1, const float* __restrict__ bs1,
    const float* __restrict__ ws2, const float* __restrict__ bs2,
    const float* __restrict__ wsh, const float* __restrict__ bsh,
    const float* __restrict__ wt0, const float* __restrict__ bt0,
    const float* __restrict__ wt1, const float* __restrict__ bt1,
    const float* __restrict__ wt2, const float* __restrict__ bt2,
    char* __restrict__ img)
{
  const float S0    = 0.10206207261596576f;                       // 1/sqrt(96)
  const float ST0   = 0.07216878364870323f;                       // 1/sqrt(192)
  const float S1R2  = 0.08838834764831845f * 1.4142135623730951f; // 1/sqrt(128)*sqrt(2)
  const float ST0R2 = ST0 * 1.4142135623730951f;

  int idx = blockIdx.x * blockDim.x + threadIdx.x;

  if (idx < 73728) {   // 144 frags * 512 halves
    int frag = idx >> 9;
    int within = idx & 511;
    int l = within >> 3, j = within & 7;
    int g = l >> 4, o16 = l & 15;
    float val;
    if (frag < 8) {                      // W0: canonical k = 8g + j (emb channel)
      val = ws0[(16 * frag + o16) * 96 + 8 * g + j] * S0;
    } else {
      int s = frag & 3;                  // region starts are multiples of 4
      int c = 16 * (2 * s + (j >> 2)) + 4 * g + (j & 3);   // pi permutation
      if (frag < 40)       { int t = (frag - 8)  >> 2; val = ws1[(16*t + o16)*128 + c] * S1R2; }
      else if (frag < 72)  { int t = (frag - 40) >> 2; val = ws2[(16*t + o16)*128 + c] * S1R2; }
      else if (frag < 104) { int t = (frag - 72) >> 2; val = wt0[(16*t + o16)*192 + c] * ST0R2; }
      else if (frag < 136) { int t = (frag - 104)>> 2; val = wt1[(16*t + o16)*128 + c] * S1R2; }
      else if (frag < 140) { val = (o16 == 0) ? wsh[c] * S1R2 : 0.f; }
      else                 { val = (o16 < 3) ? wt2[o16 * 128 + c] * S1R2 : 0.f; }
    }
    ((_Float16*)img)[idx] = (_Float16)val;
  }

  int fi = idx - 73728;
  if (fi >= 0 && fi < 2464) {
    float v; int off;
    if (fi < 1024) {            // B0eff[b][o] = bs0 + sc @ (ws0[:,32:96]*S0)^T
      int b = fi >> 7, o = fi & 127; float a = bs0[o];
      for (int q = 0; q < 64; ++q) a += sc[b*64 + q] * ws0[o*96 + 32 + q] * S0;
      v = a; off = OB0/4 + fi;
    } else if (fi < 1152) { v = bs1[fi - 1024]; off = OB1/4 + fi - 1024; }
    else if (fi < 1280)   { v = bs2[fi - 1152]; off = OB2/4 + fi - 1152; }
    else if (fi < 2304) {       // BT0eff[b][o] = bt0 + tc @ (wt0[:,128:192]*ST0)^T
      int q0 = fi - 1280; int b = q0 >> 7, o = q0 & 127; float a = bt0[o];
      for (int q = 0; q < 64; ++q) a += tc[b*64 + q] * wt0[o*192 + 128 + q] * ST0;
      v = a; off = OBT0/4 + q0;
    } else if (fi < 2432) { v = bt1[fi - 2304]; off = OBT1/4 + fi - 2304; }
    else if (fi < 2448)   { int q = fi - 2432; v = (q == 0) ? bsh[0] : 0.f; off = OBSH/4 + q; }
    else                  { int q = fi - 2448; v = (q < 3) ? bt2[q] : 0.f;  off = OBT2/4 + q; }
    ((float*)img)[off] = v;
  }
}

// ============================ main kernel ============================
__device__ __forceinline__ h2 pk2(float a, float b) {
  auto r = __builtin_amdgcn_cvt_pkrtz(a, b);
  h2 o; __builtin_memcpy(&o, &r, sizeof(o)); return o;
}
__device__ __forceinline__ float lr(float y) { return fmaxf(y, 0.2f * y); }  // sqrt(2) folded into next W

// Build a v8h from four h2 pairs — pure SSA, no union, no memory aggregate.
__device__ __forceinline__ v8h mk8(h2 a, h2 b, h2 c, h2 d) {
  v4h ab = __builtin_shufflevector(a, b, 0, 1, 2, 3);
  v4h cd = __builtin_shufflevector(c, d, 0, 1, 2, 3);
  return __builtin_shufflevector(ab, cd, 0, 1, 2, 3, 4, 5, 6, 7);
}

// Build next-layer B-frags from activated accumulators (lane-local, pi-matched)
__device__ __forceinline__ void trans(const v4f acc[8][4], v8h B[4][4]) {
#pragma unroll
  for (int n = 0; n < 4; ++n)
#pragma unroll
    for (int s = 0; s < 4; ++s) {
      B[n][s] = mk8(pk2(lr(acc[2*s  ][n][0]), lr(acc[2*s  ][n][1])),
                    pk2(lr(acc[2*s  ][n][2]), lr(acc[2*s  ][n][3])),
                    pk2(lr(acc[2*s+1][n][0]), lr(acc[2*s+1][n][1])),
                    pk2(lr(acc[2*s+1][n][2]), lr(acc[2*s+1][n][3])));
    }
}

// s-outer / t-inner: acc (128) persists (AGPR-class), one A-frag live at a time.
__device__ __forceinline__ void layer128(const char* lds, int wbase, int bbase, int boff,
                                         const v8h B[4][4], v4f acc[8][4], int l, int g) {
  const float* fB = (const float*)(lds + bbase) + boff;
#pragma unroll
  for (int t = 0; t < 8; ++t) {
    v4f bias = *(const v4f*)(fB + 16 * t + 4 * g);   // 16-lane broadcast read
#pragma unroll
    for (int n = 0; n < 4; ++n) acc[t][n] = bias;
  }
  const v8h* wf = (const v8h*)(lds + wbase);
#pragma unroll
  for (int s = 0; s < 4; ++s) {
#pragma unroll
    for (int t = 0; t < 8; ++t) {
      v8h A = wf[(t * 4 + s) * 64 + l];
#pragma unroll
      for (int n = 0; n < 4; ++n)
        acc[t][n] = __builtin_amdgcn_mfma_f32_16x16x32_f16(A, B[n][s], acc[t][n], 0, 0, 0);
    }
  }
}

__global__ __launch_bounds__(512)
__attribute__((amdgpu_waves_per_eu(2, 2)))   // budget = 512/2 = 256 regs (LDS caps us at 2 waves/SIMD anyway)
void decoder_kernel(
    const float2* __restrict__ coords, const char* __restrict__ img,
    float* __restrict__ out)
{
  __shared__ float4 ldsbuf[IMG_BYTES / 16];
  char* lds = (char*)ldsbuf;
  const int tid = threadIdx.x;
  {
    const float4* src = (const float4*)img;
    for (int i = tid; i < IMG_BYTES / 16; i += 512) ldsbuf[i] = src[i];
  }
  __syncthreads();

  const int l = tid & 63, w = tid >> 6;
  const int g = l >> 4, p16 = l & 15;

#pragma unroll 1
  for (int it = 0; it < 4; ++it) {
    const int T = blockIdx.x * 32 + w * 4 + it;   // 64-px tile index
    const int base = T * 64;
    const int b = T >> 10;                        // batch (1024 tiles / image)

    // ---- embed + radius window factor (coords die here; keep only m[4])
    v8h B[4][4];
    float m[4];
    const float e0 = 0.1f * (float)(1 << (2 * g));
#pragma unroll
    for (int n = 0; n < 4; ++n) {
      float2 c = coords[base + n * 16 + p16];
      float x0 = c.x * e0, y0 = c.y * e0;
      float sx0, cx0, sy0, cy0, sx1, cx1, sy1, cy1;
      __sincosf(x0, &sx0, &cx0); __sincosf(y0, &sy0, &cy0);
      __sincosf(x0 + x0, &sx1, &cx1); __sincosf(y0 + y0, &sy1, &cy1);
      B[n][0] = mk8(pk2(sx0, sy0), pk2(cx0, cy0), pk2(sx1, sy1), pk2(cx1, cy1));
      float rr = sqrtf(c.x * c.x + c.y * c.y);
      float y = fmaxf(rr - 1.f, 0.f);
      m[n] = 2.f / (__expf(2.f * y) + 1.f);       // 1 - tanh(relu(r-1))
    }

    v4f acc[8][4];
    // ---- L0 (K=32)
    {
      const v8h* wf = (const v8h*)(lds + OW0);
      const float* fB = (const float*)(lds + OB0) + b * 128;
#pragma unroll
      for (int t = 0; t < 8; ++t) {
        v8h A = wf[t * 64 + l];
        v4f bias = *(const v4f*)(fB + 16 * t + 4 * g);
#pragma unroll
        for (int n = 0; n < 4; ++n)
          acc[t][n] = __builtin_amdgcn_mfma_f32_16x16x32_f16(A, B[n][0], bias, 0, 0, 0);
      }
    }
    trans(acc, B);
    layer128(lds, OW1, OB1, 0, B, acc, l, g);
    trans(acc, B);
    layer128(lds, OW2, OB2, 0, B, acc, l, g);
    trans(acc, B);   // B = h fragments (used by shape head AND texture layer 0)

    // ---- shape head (M padded to 16) + radius window
    {
      v4f acch[4];
      v4f bias = *(const v4f*)((const float*)(lds + OBSH) + 4 * g);
#pragma unroll
      for (int n = 0; n < 4; ++n) acch[n] = bias;
      const v8h* wf = (const v8h*)(lds + OWSH);
#pragma unroll
      for (int s = 0; s < 4; ++s) {
        v8h A = wf[s * 64 + l];
#pragma unroll
        for (int n = 0; n < 4; ++n)
          acch[n] = __builtin_amdgcn_mfma_f32_16x16x32_f16(A, B[n][s], acch[n], 0, 0, 0);
      }
      if (g == 0) {
#pragma unroll
        for (int n = 0; n < 4; ++n)
          out[base + n * 16 + p16] = acch[n][0] * m[n];
      }
    }

    // ---- texture MLP
    layer128(lds, OWT0, OBT0, b * 128, B, acc, l, g);
    trans(acc, B);
    layer128(lds, OWT1, OBT1, 0, B, acc, l, g);
    trans(acc, B);

    // ---- texture head (rows 0..2 valid)
    {
      v4f acct[4];
      v4f bias = *(const v4f*)((const float*)(lds + OBT2) + 4 * g);
#pragma unroll
      for (int n = 0; n < 4; ++n) acct[n] = bias;
      const v8h* wf = (const v8h*)(lds + OWT2);
#pragma unroll
      for (int s = 0; s < 4; ++s) {
        v8h A = wf[s * 64 + l];
#pragma unroll
        for (int n = 0; n < 4; ++n)
          acct[n] = __builtin_amdgcn_mfma_f32_16x16x32_f16(A, B[n][s], acct[n], 0, 0, 0);
      }
      if (g == 0) {
#pragma unroll
        for (int n = 0; n < 4; ++n) {
          int ob = NPIX + 3 * (base + n * 16 + p16);
          out[ob] = acct[n][0]; out[ob + 1] = acct[n][1]; out[ob + 2] = acct[n][2];
        }
      }
    }
  }
}

extern "C" void kernel_launch(void* const* d_in, const int* in_sizes, int n_in,
                              void* d_out, int out_size, void* d_ws, size_t ws_size,
                              hipStream_t stream)
{
  const float* coords = (const float*)d_in[0];
  const float* sc  = (const float*)d_in[1];
  const float* tc  = (const float*)d_in[2];
  const float* ws0 = (const float*)d_in[3];
  const float* bs0 = (const float*)d_in[4];
  const float* ws1 = (const float*)d_in[5];
  const float* bs1 = (const float*)d_in[6];
  const float* ws2 = (const float*)d_in[7];
  const float* bs2 = (const float*)d_in[8];
  const float* wsh = (const float*)d_in[9];
  const float* bsh = (const float*)d_in[10];
  const float* wt0 = (const float*)d_in[11];
  const float* bt0 = (const float*)d_in[12];
  const float* wt1 = (const float*)d_in[13];
  const float* bt1 = (const float*)d_in[14];
  const float* wt2 = (const float*)d_in[15];
  const float* bt2 = (const float*)d_in[16];
  char* img = (char*)d_ws;
  float* out = (float*)d_out;

  hipLaunchKernelGGL(prep_kernel, dim3(298), dim3(256), 0, stream,
                     sc, tc, ws0, bs0, ws1, bs1, ws2, bs2, wsh, bsh,
                     wt0, bt0, wt1, bt1, wt2, bt2, img);
  hipLaunchKernelGGL(decoder_kernel, dim3(256), dim3(512), 0, stream,
                     (const float2*)coords, img, out);
}